// Round 1
// baseline (845.426 us; speedup 1.0000x reference)
//
#include <hip/hip_runtime.h>
#include <math.h>

#define TS 64
#define KT 16
#define LDP 68   // padded leading dim: stride 68 floats = 272B, 16B-aligned rows, conflict-benign

// C[row,col] = act(A[row,:] . Bw[col,:] + bias[col]);  A:[M,K], Bw:[N,K] row-major (i.e. X @ W^T)
__global__ __launch_bounds__(256) void gemm_bt(const float* __restrict__ A,
                                               const float* __restrict__ Bw,
                                               const float* __restrict__ bias,
                                               float* __restrict__ C,
                                               int M, int N, int K, int do_relu)
{
    __shared__ float As[KT][LDP];   // As[k][i] : A rows transposed
    __shared__ float Bs[KT][LDP];   // Bs[k][j] : Bw rows transposed
    const int tid = threadIdx.x;
    const int tx = tid & 15, ty = tid >> 4;
    const int row0 = blockIdx.y * TS, col0 = blockIdx.x * TS;
    const int li = tid >> 2;            // 0..63
    const int lk = (tid & 3) << 2;      // {0,4,8,12}
    float acc[4][4] = {};

    for (int k0 = 0; k0 < K; k0 += KT) {
        float4 a4 = *(const float4*)(A  + (size_t)(row0 + li) * K + k0 + lk);
        float4 b4 = *(const float4*)(Bw + (size_t)(col0 + li) * K + k0 + lk);
        __syncthreads();   // previous iteration's compute reads done
        As[lk+0][li] = a4.x; As[lk+1][li] = a4.y; As[lk+2][li] = a4.z; As[lk+3][li] = a4.w;
        Bs[lk+0][li] = b4.x; Bs[lk+1][li] = b4.y; Bs[lk+2][li] = b4.z; Bs[lk+3][li] = b4.w;
        __syncthreads();
        #pragma unroll
        for (int k = 0; k < KT; ++k) {
            float4 av = *(const float4*)&As[k][ty << 2];
            float4 bv = *(const float4*)&Bs[k][tx << 2];
            float ar[4] = {av.x, av.y, av.z, av.w};
            float br[4] = {bv.x, bv.y, bv.z, bv.w};
            #pragma unroll
            for (int r = 0; r < 4; ++r)
                #pragma unroll
                for (int c = 0; c < 4; ++c)
                    acc[r][c] = fmaf(ar[r], br[c], acc[r][c]);
        }
    }

    #pragma unroll
    for (int r = 0; r < 4; ++r) {
        const int row = row0 + (ty << 2) + r;
        #pragma unroll
        for (int c = 0; c < 4; ++c) {
            const int col = col0 + (tx << 2) + c;
            float v = acc[r][c] + bias[col];
            if (do_relu) v = fmaxf(v, 0.f);
            C[(size_t)row * N + col] = v;
        }
    }
}

// Flash-style causal synthesizer attention.
// Kmat/Vmat: [B*T, C] fp32. w2: [H, hd, M]. b2: [M]. Omat: [B*T, C].
// Block = 256 threads handles 64 query rows of one (b,h). Grid = (T/64, H, B).
__global__ __launch_bounds__(256) void synth_attn(const float* __restrict__ Kmat,
                                                  const float* __restrict__ Vmat,
                                                  const float* __restrict__ w2,
                                                  const float* __restrict__ b2,
                                                  float* __restrict__ Omat,
                                                  int B, int T, int C, int H, int M)
{
    const int hd = C / H;                 // 64
    __shared__ float Kst[64][LDP];        // [d][i]  K-block transposed
    __shared__ float WtPs[64][LDP];       // phase 1: [d][j] = w2 tile; phase 2: [j][i] = P transposed
    __shared__ float Vt[64][LDP];         // [j][d]
    const int tid = threadIdx.x;
    const int tx = tid & 15, ty = tid >> 4;
    const int tb = blockIdx.x, h = blockIdx.y, b = blockIdx.z;
    const int t0 = tb * 64;

    // stage K block transposed: Kst[d][i] = Kmat[b*T+t0+i, h*hd+d]
    {
        const int i  = tid >> 2;
        const int d0 = (tid & 3) << 4;
        const float* src = Kmat + (size_t)(b * T + t0 + i) * C + h * hd + d0;
        #pragma unroll
        for (int q = 0; q < 4; ++q) {
            float4 v = *(const float4*)(src + 4 * q);
            Kst[d0 + 4*q + 0][i] = v.x;
            Kst[d0 + 4*q + 1][i] = v.y;
            Kst[d0 + 4*q + 2][i] = v.z;
            Kst[d0 + 4*q + 3][i] = v.w;
        }
    }

    float m[4], l[4], acc[4][4];
    #pragma unroll
    for (int r = 0; r < 4; ++r) {
        m[r] = -INFINITY; l[r] = 0.f;
        #pragma unroll
        for (int c = 0; c < 4; ++c) acc[r][c] = 0.f;
    }

    for (int sb = 0; sb <= tb; ++sb) {
        const int s0 = sb * 64;
        __syncthreads();   // previous tile's PV reads done (and Kst staged on first iter)
        // stage Wt (into WtPs) and Vt
        {
            const int rr = tid >> 2;            // d for Wt, j for Vt
            const int c0 = (tid & 3) << 4;
            const float* srcw = w2   + ((size_t)h * hd + rr) * M + s0 + c0;
            const float* srcv = Vmat + (size_t)(b * T + s0 + rr) * C + h * hd + c0;
            #pragma unroll
            for (int q = 0; q < 4; ++q) {
                *(float4*)&WtPs[rr][c0 + 4*q] = *(const float4*)(srcw + 4*q);
                *(float4*)&Vt  [rr][c0 + 4*q] = *(const float4*)(srcv + 4*q);
            }
        }
        __syncthreads();

        // S[i][j] = sum_d Kst[d][i] * Wt[d][j]
        float s[4][4] = {};
        #pragma unroll 8
        for (int d = 0; d < 64; ++d) {
            float4 av = *(const float4*)&Kst[d][ty << 2];
            float4 bv = *(const float4*)&WtPs[d][tx << 2];
            float ar[4] = {av.x, av.y, av.z, av.w};
            float br[4] = {bv.x, bv.y, bv.z, bv.w};
            #pragma unroll
            for (int r = 0; r < 4; ++r)
                #pragma unroll
                for (int c = 0; c < 4; ++c)
                    s[r][c] = fmaf(ar[r], br[c], s[r][c]);
        }
        __syncthreads();   // all S reads of Wt done before P overwrites it

        // bias + causal mask
        #pragma unroll
        for (int c = 0; c < 4; ++c) {
            const float bb = b2[s0 + (tx << 2) + c];
            #pragma unroll
            for (int r = 0; r < 4; ++r) s[r][c] += bb;
        }
        if (sb == tb) {
            #pragma unroll
            for (int r = 0; r < 4; ++r)
                #pragma unroll
                for (int c = 0; c < 4; ++c)
                    if (((tx << 2) + c) > ((ty << 2) + r)) s[r][c] = -INFINITY;
        }

        // online softmax (row state replicated across the 16 lanes of each row group)
        float p[4][4];
        #pragma unroll
        for (int r = 0; r < 4; ++r) {
            float rm = fmaxf(fmaxf(s[r][0], s[r][1]), fmaxf(s[r][2], s[r][3]));
            rm = fmaxf(rm, __shfl_xor(rm, 1));
            rm = fmaxf(rm, __shfl_xor(rm, 2));
            rm = fmaxf(rm, __shfl_xor(rm, 4));
            rm = fmaxf(rm, __shfl_xor(rm, 8));
            const float mn = fmaxf(m[r], rm);
            const float scale = __expf(m[r] - mn);
            float rs = 0.f;
            #pragma unroll
            for (int c = 0; c < 4; ++c) {
                p[r][c] = __expf(s[r][c] - mn);   // masked: exp(-inf)=0
                rs += p[r][c];
            }
            rs += __shfl_xor(rs, 1);
            rs += __shfl_xor(rs, 2);
            rs += __shfl_xor(rs, 4);
            rs += __shfl_xor(rs, 8);
            l[r] = l[r] * scale + rs;
            m[r] = mn;
            #pragma unroll
            for (int c = 0; c < 4; ++c) acc[r][c] *= scale;
        }
        // write P transposed into WtPs[j][i]
        #pragma unroll
        for (int r = 0; r < 4; ++r)
            #pragma unroll
            for (int c = 0; c < 4; ++c)
                WtPs[(tx << 2) + c][(ty << 2) + r] = p[r][c];
        __syncthreads();

        // O[i][d] += sum_j P[i][j] * Vt[j][d]
        #pragma unroll 8
        for (int j = 0; j < 64; ++j) {
            float4 pv = *(const float4*)&WtPs[j][ty << 2];
            float4 vv = *(const float4*)&Vt[j][tx << 2];
            float pr[4] = {pv.x, pv.y, pv.z, pv.w};
            float vr[4] = {vv.x, vv.y, vv.z, vv.w};
            #pragma unroll
            for (int r = 0; r < 4; ++r)
                #pragma unroll
                for (int c = 0; c < 4; ++c)
                    acc[r][c] = fmaf(pr[r], vr[c], acc[r][c]);
        }
    }

    // normalize and store O in [B*T, C] layout
    #pragma unroll
    for (int r = 0; r < 4; ++r) {
        const float inv = 1.f / l[r];
        const int row = b * T + t0 + (ty << 2) + r;
        #pragma unroll
        for (int c = 0; c < 4; ++c)
            Omat[(size_t)row * C + h * hd + (tx << 2) + c] = acc[r][c] * inv;
    }
}

extern "C" void kernel_launch(void* const* d_in, const int* in_sizes, int n_in,
                              void* d_out, int out_size, void* d_ws, size_t ws_size,
                              hipStream_t stream) {
    const float* x       = (const float*)d_in[0];
    const float* w1_w    = (const float*)d_in[1];
    const float* w1_b    = (const float*)d_in[2];
    const float* w2      = (const float*)d_in[3];
    const float* b2      = (const float*)d_in[4];
    const float* value_w = (const float*)d_in[5];
    const float* value_b = (const float*)d_in[6];
    const float* proj_w  = (const float*)d_in[7];
    const float* proj_b  = (const float*)d_in[8];
    float* out = (float*)d_out;

    const int B = 2, T = 2048, C = 1024, H = 16, M = 2048;
    const int Mrows = B * T;   // 4096

    float* Kmat = (float*)d_ws;                       // 16 MB
    float* Vmat = Kmat + (size_t)Mrows * C;           // 16 MB
    float* Omat = Vmat + (size_t)Mrows * C;           // 16 MB

    dim3 blk(256);
    dim3 g1(C / TS, Mrows / TS);   // (16, 64)
    gemm_bt<<<g1, blk, 0, stream>>>(x, w1_w, w1_b, Kmat, Mrows, C, C, 1);
    gemm_bt<<<g1, blk, 0, stream>>>(x, value_w, value_b, Vmat, Mrows, C, C, 0);

    dim3 g2(T / 64, H, B);         // (32, 16, 2)
    synth_attn<<<g2, blk, 0, stream>>>(Kmat, Vmat, w2, b2, Omat, B, T, C, H, M);

    gemm_bt<<<g1, blk, 0, stream>>>(Omat, proj_w, proj_b, out, Mrows, C, C, 0);
}

// Round 2
// 201.582 us; speedup vs baseline: 4.1940x; 4.1940x over previous
//
#include <hip/hip_runtime.h>
#include <math.h>
#include <stdint.h>

typedef __bf16 bf16;
typedef __bf16 bf16x8 __attribute__((ext_vector_type(8)));
typedef __bf16 bf16x4 __attribute__((ext_vector_type(4)));
typedef float f32x4 __attribute__((ext_vector_type(4)));

// element index into a [rows][64] bf16 tile, XOR-swizzled in 16B (8-elem) chunks
__device__ __forceinline__ int swz(int row, int chunk) {
    return row * 64 + ((chunk ^ (row & 7)) << 3);
}

__global__ void cast_bf16_k(const float* __restrict__ src, bf16* __restrict__ dst, int n) {
    const int stride = gridDim.x * blockDim.x * 4;
    for (int i = (blockIdx.x * blockDim.x + threadIdx.x) * 4; i < n; i += stride) {
        float4 v = *(const float4*)(src + i);
        bf16x4 o = {(bf16)v.x, (bf16)v.y, (bf16)v.z, (bf16)v.w};
        *(bf16x4*)(dst + i) = o;
    }
}

// w2 [H][64][M] f32  ->  w2t [H][M][64] bf16
__global__ __launch_bounds__(256) void w2_transpose_k(const float* __restrict__ w2,
                                                      bf16* __restrict__ w2t, int M) {
    __shared__ float Tf[64][65];
    const int h = blockIdx.y, m0 = blockIdx.x * 64, t = threadIdx.x;
    {
        const int dr = t >> 4, c4 = (t & 15) * 4;
        #pragma unroll
        for (int it = 0; it < 4; ++it) {
            const int d = dr + it * 16;
            float4 v = *(const float4*)(w2 + ((size_t)h * 64 + d) * M + m0 + c4);
            Tf[d][c4] = v.x; Tf[d][c4 + 1] = v.y; Tf[d][c4 + 2] = v.z; Tf[d][c4 + 3] = v.w;
        }
    }
    __syncthreads();
    const int m = t >> 2;
    #pragma unroll
    for (int it = 0; it < 2; ++it) {
        const int ch = (t & 3) + it * 4;
        bf16x8 o;
        #pragma unroll
        for (int j = 0; j < 8; ++j) o[j] = (bf16)Tf[ch * 8 + j][m];
        *(bf16x8*)(w2t + ((size_t)h * M + m0 + m) * 64 + ch * 8) = o;
    }
}

// 128x128x64 bf16 MFMA GEMM, A[M][K] row-major, Bw[N][K] row-major (X @ W^T).
// mode 0: C0[M][N] fp32 = acc + bias
// mode 1: fused KV: col <  Ns -> CK[M][Ns] bf16 = relu(acc + bias)
//                   col >= Ns -> CV = VT[b][col-Ns][2048] bf16 = acc + bias2  (transposed store)
__global__ __launch_bounds__(256) void gemm_bf16_k(const bf16* __restrict__ A,
                                                   const bf16* __restrict__ Bw,
                                                   const float* __restrict__ bias,
                                                   const float* __restrict__ bias2,
                                                   float* __restrict__ C0,
                                                   bf16* __restrict__ CK,
                                                   bf16* __restrict__ CV,
                                                   int M, int N, int K, int mode, int Ns)
{
    __shared__ __align__(16) bf16 As[128 * 64];
    __shared__ __align__(16) bf16 Bs[128 * 64];
    const int tid = threadIdx.x;
    const int w = tid >> 6, l = tid & 63;
    const int wr = w >> 1, wc = w & 1;
    const int lc = l & 15, lg = l >> 4;
    const int row0 = blockIdx.y * 128, col0 = blockIdx.x * 128;

    f32x4 acc[4][4] = {};

    for (int k0 = 0; k0 < K; k0 += 64) {
        __syncthreads();
        #pragma unroll
        for (int i = 0; i < 4; ++i) {
            const int c = i * 256 + tid;
            const int r = c >> 3, g = c & 7;
            bf16x8 va = *(const bf16x8*)(A  + (size_t)(row0 + r) * K + k0 + g * 8);
            bf16x8 vb = *(const bf16x8*)(Bw + (size_t)(col0 + r) * K + k0 + g * 8);
            *(bf16x8*)&As[swz(r, g)] = va;
            *(bf16x8*)&Bs[swz(r, g)] = vb;
        }
        __syncthreads();
        #pragma unroll
        for (int ks = 0; ks < 2; ++ks) {
            bf16x8 af[4], bfv[4];
            #pragma unroll
            for (int i = 0; i < 4; ++i) {
                af[i]  = *(const bf16x8*)&As[swz(wr * 64 + i * 16 + lc, ks * 4 + lg)];
                bfv[i] = *(const bf16x8*)&Bs[swz(wc * 64 + i * 16 + lc, ks * 4 + lg)];
            }
            #pragma unroll
            for (int mi = 0; mi < 4; ++mi)
                #pragma unroll
                for (int ni = 0; ni < 4; ++ni)
                    acc[mi][ni] = __builtin_amdgcn_mfma_f32_16x16x32_bf16(af[mi], bfv[ni], acc[mi][ni], 0, 0, 0);
        }
    }

    #pragma unroll
    for (int ni = 0; ni < 4; ++ni) {
        const int col = col0 + wc * 64 + ni * 16 + lc;
        #pragma unroll
        for (int mi = 0; mi < 4; ++mi) {
            const int rowb = row0 + wr * 64 + mi * 16 + lg * 4;
            f32x4 v = acc[mi][ni];
            if (mode == 0) {
                const float bv = bias[col];
                #pragma unroll
                for (int r = 0; r < 4; ++r)
                    C0[(size_t)(rowb + r) * N + col] = v[r] + bv;
            } else if (col < Ns) {
                const float bv = bias[col];
                #pragma unroll
                for (int r = 0; r < 4; ++r)
                    CK[(size_t)(rowb + r) * Ns + col] = (bf16)fmaxf(v[r] + bv, 0.f);
            } else {
                const float bv = bias2[col - Ns];
                const int b = rowb >> 11, tt = rowb & 2047;   // T = 2048
                bf16x4 o = {(bf16)(v[0] + bv), (bf16)(v[1] + bv),
                            (bf16)(v[2] + bv), (bf16)(v[3] + bv)};
                *(bf16x4*)(CV + ((size_t)b * Ns + (col - Ns)) * 2048 + tt) = o;
            }
        }
    }
}

// Flash-style causal synthesizer attention, bf16 MFMA.
// Kb [B*T][C] bf16, VT [B][C][T] bf16, w2t [H][M][64] bf16, b2 [M] f32 -> Ob [B*T][C] bf16
__global__ __launch_bounds__(256) void synth_attn_mfma_k(const bf16* __restrict__ Kb,
                                                         const bf16* __restrict__ VT,
                                                         const bf16* __restrict__ w2t,
                                                         const float* __restrict__ b2,
                                                         bf16* __restrict__ Ob)
{
    constexpr int T = 2048, C = 1024, M = 2048;
    __shared__ __align__(16) bf16 Kl[64 * 64];
    __shared__ __align__(16) bf16 Wl[64 * 64];
    __shared__ __align__(16) bf16 Vl[64 * 64];
    __shared__ __align__(16) bf16 Pl[64 * 64];
    const int tid = threadIdx.x;
    const int w = tid >> 6, l = tid & 63;
    const int lc = l & 15, lg = l >> 4;
    const int tb = blockIdx.x, h = blockIdx.y, b = blockIdx.z;
    const int t0 = tb * 64;

    #pragma unroll
    for (int i = 0; i < 2; ++i) {
        const int c = i * 256 + tid;
        const int r = c >> 3, g = c & 7;
        *(bf16x8*)&Kl[swz(r, g)] = *(const bf16x8*)(Kb + (size_t)(b * T + t0 + r) * C + h * 64 + g * 8);
    }

    f32x4 acc[4] = {};
    float mrow[4] = {-INFINITY, -INFINITY, -INFINITY, -INFINITY};
    float lrow[4] = {0.f, 0.f, 0.f, 0.f};

    const bf16* Wg = w2t + (size_t)h * M * 64;
    const bf16* Vg = VT + ((size_t)b * C + h * 64) * T;

    for (int sb = 0; sb <= tb; ++sb) {
        const int s0 = sb * 64;
        __syncthreads();
        #pragma unroll
        for (int i = 0; i < 2; ++i) {
            const int c = i * 256 + tid;
            const int r = c >> 3, g = c & 7;
            *(bf16x8*)&Wl[swz(r, g)] = *(const bf16x8*)(Wg + (size_t)(s0 + r) * 64 + g * 8);
            *(bf16x8*)&Vl[swz(r, g)] = *(const bf16x8*)(Vg + (size_t)r * T + s0 + g * 8);
        }
        __syncthreads();

        // S = K . W2  (rows: this wave's 16 t's; cols: 64 s's)
        f32x4 s[4] = {};
        #pragma unroll
        for (int ks = 0; ks < 2; ++ks) {
            bf16x8 af = *(const bf16x8*)&Kl[swz(w * 16 + lc, ks * 4 + lg)];
            #pragma unroll
            for (int st = 0; st < 4; ++st) {
                bf16x8 bv = *(const bf16x8*)&Wl[swz(st * 16 + lc, ks * 4 + lg)];
                s[st] = __builtin_amdgcn_mfma_f32_16x16x32_bf16(af, bv, s[st], 0, 0, 0);
            }
        }

        #pragma unroll
        for (int st = 0; st < 4; ++st) {
            const float bb = b2[s0 + st * 16 + lc];
            #pragma unroll
            for (int r = 0; r < 4; ++r) s[st][r] += bb;
        }
        if (sb == tb) {
            #pragma unroll
            for (int st = 0; st < 4; ++st) {
                const int scol = st * 16 + lc;
                #pragma unroll
                for (int r = 0; r < 4; ++r)
                    if (scol > w * 16 + lg * 4 + r) s[st][r] = -INFINITY;
            }
        }

        // online softmax; row state replicated across the 16 lanes of each lg-group
        #pragma unroll
        for (int r = 0; r < 4; ++r) {
            float rm = fmaxf(fmaxf(s[0][r], s[1][r]), fmaxf(s[2][r], s[3][r]));
            rm = fmaxf(rm, __shfl_xor(rm, 1));
            rm = fmaxf(rm, __shfl_xor(rm, 2));
            rm = fmaxf(rm, __shfl_xor(rm, 4));
            rm = fmaxf(rm, __shfl_xor(rm, 8));
            const float mn = fmaxf(mrow[r], rm);
            const float sc = __expf(mrow[r] - mn);
            float rs = 0.f;
            #pragma unroll
            for (int st = 0; st < 4; ++st) {
                const float p = __expf(s[st][r] - mn);
                s[st][r] = p;
                rs += p;
            }
            rs += __shfl_xor(rs, 1);
            rs += __shfl_xor(rs, 2);
            rs += __shfl_xor(rs, 4);
            rs += __shfl_xor(rs, 8);
            lrow[r] = lrow[r] * sc + rs;
            mrow[r] = mn;
            #pragma unroll
            for (int dt = 0; dt < 4; ++dt) acc[dt][r] *= sc;
        }

        // P -> LDS (bf16, swizzled)
        #pragma unroll
        for (int st = 0; st < 4; ++st) {
            const int scol = st * 16 + lc;
            #pragma unroll
            for (int r = 0; r < 4; ++r) {
                const int trow = w * 16 + lg * 4 + r;
                Pl[trow * 64 + (((scol >> 3) ^ (trow & 7)) << 3) + (scol & 7)] = (bf16)s[st][r];
            }
        }
        __syncthreads();

        // O += P . V
        #pragma unroll
        for (int ks = 0; ks < 2; ++ks) {
            bf16x8 pf = *(const bf16x8*)&Pl[swz(w * 16 + lc, ks * 4 + lg)];
            #pragma unroll
            for (int dt = 0; dt < 4; ++dt) {
                bf16x8 vv = *(const bf16x8*)&Vl[swz(dt * 16 + lc, ks * 4 + lg)];
                acc[dt] = __builtin_amdgcn_mfma_f32_16x16x32_bf16(pf, vv, acc[dt], 0, 0, 0);
            }
        }
    }

    #pragma unroll
    for (int r = 0; r < 4; ++r) {
        const float inv = 1.f / lrow[r];
        bf16* dst = Ob + (size_t)(b * T + t0 + w * 16 + lg * 4 + r) * C + h * 64;
        #pragma unroll
        for (int dt = 0; dt < 4; ++dt)
            dst[dt * 16 + lc] = (bf16)(acc[dt][r] * inv);
    }
}

extern "C" void kernel_launch(void* const* d_in, const int* in_sizes, int n_in,
                              void* d_out, int out_size, void* d_ws, size_t ws_size,
                              hipStream_t stream) {
    const float* x       = (const float*)d_in[0];
    const float* w1_w    = (const float*)d_in[1];
    const float* w1_b    = (const float*)d_in[2];
    const float* w2      = (const float*)d_in[3];
    const float* b2      = (const float*)d_in[4];
    const float* value_w = (const float*)d_in[5];
    const float* value_b = (const float*)d_in[6];
    const float* proj_w  = (const float*)d_in[7];
    const float* proj_b  = (const float*)d_in[8];

    const int B = 2, T = 2048, C = 1024, H = 16, M = 2048;
    const int R = B * T;   // 4096

    bf16* xb  = (bf16*)d_ws;                  // [R][C]
    bf16* w1b = xb  + (size_t)R * C;          // [C][C]   } contiguous ->
    bf16* vwb = w1b + (size_t)C * C;          // [C][C]   } fused B [2C][C]
    bf16* w2t = vwb + (size_t)C * C;          // [H][M][64]
    bf16* pwb = w2t + (size_t)H * M * 64;     // [C][C]
    bf16* Kb  = pwb + (size_t)C * C;          // [R][C]
    bf16* VTb = Kb  + (size_t)R * C;          // [B][C][T]
    bf16* Ob  = VTb + (size_t)R * C;          // [R][C]    total 42 MB

    cast_bf16_k<<<1024, 256, 0, stream>>>(x, xb, R * C);
    cast_bf16_k<<<256, 256, 0, stream>>>(w1_w, w1b, C * C);
    cast_bf16_k<<<256, 256, 0, stream>>>(value_w, vwb, C * C);
    cast_bf16_k<<<256, 256, 0, stream>>>(proj_w, pwb, C * C);
    w2_transpose_k<<<dim3(M / 64, H), 256, 0, stream>>>(w2, w2t, M);

    // fused K/V GEMM: N = 2C, B-operand = [w1b ; vwb]
    gemm_bf16_k<<<dim3(2 * C / 128, R / 128), 256, 0, stream>>>(
        xb, w1b, w1_b, value_b, nullptr, Kb, VTb, R, 2 * C, C, 1, C);

    synth_attn_mfma_k<<<dim3(T / 64, H, B), 256, 0, stream>>>(Kb, VTb, w2t, b2, Ob);

    gemm_bf16_k<<<dim3(C / 128, R / 128), 256, 0, stream>>>(
        Ob, pwb, proj_b, nullptr, (float*)d_out, nullptr, nullptr, R, C, C, 0, C);
}